// Round 1
// baseline (190.906 us; speedup 1.0000x reference)
//
#include <hip/hip_runtime.h>

// MpMaxPoolingMatch: out[b,t,m] = tanh( max_s sum_d lt[b,t,d]*km[m,d]*rt[b,s,d] )
// B=32, T=256, D=512, MP=20. Compute-bound (43 GFLOP, 34 MB inputs) -> bf16 MFMA.
// Block = (t_tile, m, b): NT-GEMM (lt .* km_m) @ rt^T, BM=128 x BN=256 (full s) x BK=32,
// 4 waves of 64x128 (4 m-pos x 8 n-pos, 16x16x32 bf16), km-scaling fused into A staging,
// double-buffered LDS, running max via elementwise frag max + xor-shuffle, tanh epilogue.

constexpr int TT = 256;   // T
constexpr int DD = 512;   // D
constexpr int NM = 20;    // MP
constexpr int NB = 32;    // B
constexpr int BM = 128;
constexpr int BN = 256;
constexpr int BK = 32;
constexpr int NKSTEP = DD / BK;   // 16

typedef short bf16x8 __attribute__((ext_vector_type(8)));
typedef float f32x4  __attribute__((ext_vector_type(4)));

__device__ __forceinline__ unsigned pack_bf16(float lo, float hi) {
    // truncate-to-bf16 (round toward zero in mantissa) - error budget is huge (tanh saturation)
    unsigned ulo = __builtin_bit_cast(unsigned, lo);
    unsigned uhi = __builtin_bit_cast(unsigned, hi);
    return (ulo >> 16) | (uhi & 0xFFFF0000u);
}

__global__ __launch_bounds__(256, 2)
void mp_match_kernel(const float* __restrict__ lt, const float* __restrict__ rt,
                     const float* __restrict__ km, float* __restrict__ out)
{
    // LDS: [buf][dpart(4)][row][8 bf16]  (dpart = k_local/8 matches A/B-frag k = (lane>>4)*8+j)
    __shared__ __attribute__((aligned(16))) unsigned short Ash[2][4][BM][8]; // 2 x 8 KB
    __shared__ __attribute__((aligned(16))) unsigned short Bsh[2][4][BN][8]; // 2 x 16 KB
    __shared__ __attribute__((aligned(16))) float maxbuf[2][BM];             // 1 KB

    const int ttile = blockIdx.x;   // 0..1
    const int m     = blockIdx.y;   // 0..19
    const int b     = blockIdx.z;   // 0..31
    const int t0    = ttile * BM;

    const int tid  = threadIdx.x;
    const int wave = tid >> 6;
    const int lane = tid & 63;
    const int l15  = lane & 15;
    const int l4   = lane >> 4;
    const int wt   = (wave & 1) * 64;   // wave's t offset within tile
    const int wsi  = wave >> 1;         // wave's s-half (0: s 0..127, 1: s 128..255)

    const float* ltp = lt + ((size_t)b * TT + t0) * DD;
    const float* rtp = rt + (size_t)b * TT * DD;
    const float* kmp = km + (size_t)m * DD;

    // A staging assignment: thread -> (t row, d half of BK)
    const int a_t = tid >> 1;
    const int a_h = tid & 1;

    f32x4 acc[4][8] = {};   // [m-pos][n-pos], zero-init

    auto stage = [&](int kk, int buf) {
        const int d0 = kk * BK;
        // ---- A: 128 x 32, scaled by km row m, fp32 -> bf16. 16 elems/thread.
        const float* ap = ltp + (size_t)a_t * DD + d0 + a_h * 16;
        const float* kp = kmp + d0 + a_h * 16;
#pragma unroll
        for (int q = 0; q < 2; ++q) {   // dpart = a_h*2 + q
            float4 x0 = *(const float4*)(ap + q * 8);
            float4 x1 = *(const float4*)(ap + q * 8 + 4);
            float4 k0 = *(const float4*)(kp + q * 8);
            float4 k1 = *(const float4*)(kp + q * 8 + 4);
            uint4 w;
            w.x = pack_bf16(x0.x * k0.x, x0.y * k0.y);
            w.y = pack_bf16(x0.z * k0.z, x0.w * k0.w);
            w.z = pack_bf16(x1.x * k1.x, x1.y * k1.y);
            w.w = pack_bf16(x1.z * k1.z, x1.w * k1.w);
            *(uint4*)&Ash[buf][a_h * 2 + q][a_t][0] = w;
        }
        // ---- B: 256 x 32, fp32 -> bf16. One s-row (32 elems) per thread.
        const float* bp = rtp + (size_t)tid * DD + d0;
#pragma unroll
        for (int p = 0; p < 4; ++p) {
            float4 y0 = *(const float4*)(bp + p * 8);
            float4 y1 = *(const float4*)(bp + p * 8 + 4);
            uint4 w;
            w.x = pack_bf16(y0.x, y0.y);
            w.y = pack_bf16(y0.z, y0.w);
            w.z = pack_bf16(y1.x, y1.y);
            w.w = pack_bf16(y1.z, y1.w);
            *(uint4*)&Bsh[buf][p][tid][0] = w;
        }
    };

    stage(0, 0);

    for (int kk = 0; kk < NKSTEP; ++kk) {
        const int buf = kk & 1;
        __syncthreads();   // staging of `buf` complete; prior reads of buf^1 drained
        bf16x8 af[4], bfv[8];
#pragma unroll
        for (int i = 0; i < 4; ++i)
            af[i] = *(const bf16x8*)&Ash[buf][l4][wt + i * 16 + l15][0];
#pragma unroll
        for (int j = 0; j < 8; ++j)
            bfv[j] = *(const bf16x8*)&Bsh[buf][l4][wsi * 128 + j * 16 + l15][0];
        if (kk + 1 < NKSTEP) stage(kk + 1, buf ^ 1);   // overlap staging with MFMA
#pragma unroll
        for (int i = 0; i < 4; ++i)
#pragma unroll
            for (int j = 0; j < 8; ++j)
                acc[i][j] = __builtin_amdgcn_mfma_f32_16x16x32_bf16(af[i], bfv[j], acc[i][j], 0, 0, 0);
    }

    // ---- Epilogue: max over s (cols), then tanh.
    // C layout (16x16): col(s) = lane&15, row(t) = (lane>>4)*4 + reg.
#pragma unroll
    for (int i = 0; i < 4; ++i) {
        f32x4 v = acc[i][0];
#pragma unroll
        for (int j = 1; j < 8; ++j) {
            v.x = fmaxf(v.x, acc[i][j].x);
            v.y = fmaxf(v.y, acc[i][j].y);
            v.z = fmaxf(v.z, acc[i][j].z);
            v.w = fmaxf(v.w, acc[i][j].w);
        }
#pragma unroll
        for (int off = 1; off < 16; off <<= 1) {   // reduce over the 16 s-columns (low nibble)
            v.x = fmaxf(v.x, __shfl_xor(v.x, off, 64));
            v.y = fmaxf(v.y, __shfl_xor(v.y, off, 64));
            v.z = fmaxf(v.z, __shfl_xor(v.z, off, 64));
            v.w = fmaxf(v.w, __shfl_xor(v.w, off, 64));
        }
        if (l15 == 0) {
            // rows wt + i*16 + l4*4 .. +3 hold max over this wave's 128 s
            *(f32x4*)&maxbuf[wsi][wt + i * 16 + l4 * 4] = v;
        }
    }
    __syncthreads();
    if (tid < BM) {
        float v = fmaxf(maxbuf[0][tid], maxbuf[1][tid]);
        out[((size_t)b * TT + t0 + tid) * NM + m] = tanhf(v);
    }
}

extern "C" void kernel_launch(void* const* d_in, const int* in_sizes, int n_in,
                              void* d_out, int out_size, void* d_ws, size_t ws_size,
                              hipStream_t stream) {
    const float* lt  = (const float*)d_in[0];   // (32,256,512) fp32
    const float* rt  = (const float*)d_in[1];   // (32,256,512) fp32
    const float* km  = (const float*)d_in[2];   // (20,512) fp32
    float*       out = (float*)d_out;           // (32,256,20) fp32

    dim3 grid(TT / BM, NM, NB);                 // (2, 20, 32) = 1280 blocks
    mp_match_kernel<<<grid, 256, 0, stream>>>(lt, rt, km, out);
}

// Round 2
// 141.536 us; speedup vs baseline: 1.3488x; 1.3488x over previous
//
#include <hip/hip_runtime.h>

// MpMaxPoolingMatch: out[b,t,m] = tanh( max_s sum_d lt[b,t,d]*km[m,d]*rt[b,s,d] )
// B=32, T=256, D=512, MP=20.
// R2: phase-1 packs lt/rt fp32->bf16 into LDS-tile format in d_ws; main kernel
// stages B via global_load_lds (direct-to-LDS DMA, coalesced), A via packed bf16
// loads + km-scale (v_perm repack) + ds_write. One barrier per K-step.

constexpr int TT = 256;   // T
constexpr int DD = 512;   // D
constexpr int NM = 20;    // MP
constexpr int NB = 32;    // B
constexpr int BM = 128;
constexpr int BN = 256;
constexpr int BK = 32;
constexpr int NK = DD / BK;   // 16

typedef short bf16x8 __attribute__((ext_vector_type(8)));
typedef float f32x4  __attribute__((ext_vector_type(4)));

__device__ __forceinline__ void async_ld16(const void* g, void* l) {
    __builtin_amdgcn_global_load_lds(
        (const __attribute__((address_space(1))) void*)g,
        (__attribute__((address_space(3))) void*)l, 16, 0, 0);
}

__device__ __forceinline__ unsigned pack_bf16(float lo, float hi) {
    unsigned ulo = __builtin_bit_cast(unsigned, lo);
    unsigned uhi = __builtin_bit_cast(unsigned, hi);
    return (ulo >> 16) | (uhi & 0xFFFF0000u);
}

// scale a packed bf16 pair by two f32 km values, repack (truncate) via v_perm
__device__ __forceinline__ unsigned mulpack(unsigned a2, float k0, float k1) {
    float f0 = __builtin_bit_cast(float, a2 << 16) * k0;
    float f1 = __builtin_bit_cast(float, a2 & 0xFFFF0000u) * k1;
    return __builtin_amdgcn_perm(__builtin_bit_cast(unsigned, f1),
                                 __builtin_bit_cast(unsigned, f0), 0x07060302u);
}

// ---------------- Phase 1: fp32 -> bf16, packed into LDS-tile slot order ----------------
// dst[b][tile][kk][p][r][8bf16], slot 16B chunks; tile rows = 1<<rpt_shift (128 for lt, 256 for rt).
// Block: (b, 32-row chunk). Reads coalesced, LDS bounce, writes coalesced 16B chunks.
__global__ __launch_bounds__(256)
void pack_tiles(const float* __restrict__ src, unsigned short* __restrict__ dst, int rpt_shift)
{
    __shared__ __attribute__((aligned(16))) unsigned short buf[32][520];  // +8 pad breaks 64B-stride conflicts
    const int b  = blockIdx.x >> 3;
    const int s0 = (blockIdx.x & 7) * 32;
    const int tid = threadIdx.x;
    const float* sp = src + ((size_t)b * TT + s0) * DD;

#pragma unroll
    for (int i = 0; i < 32; ++i) {
        int idx = i * 256 + tid;                 // f32-pair index in [0, 8192)
        float2 v = *(const float2*)(sp + (size_t)idx * 2);
        unsigned pk = pack_bf16(v.x, v.y);
        int row = idx >> 8, pcol = idx & 255;
        *(unsigned*)&buf[row][pcol * 2] = pk;
    }
    __syncthreads();

    const int ntiles = TT >> rpt_shift;
    const int rmask  = (1 << rpt_shift) - 1;
#pragma unroll
    for (int it = 0; it < 8; ++it) {
        int cid = it * 256 + tid;                // chunk id in [0, 2048): 16 kk x 4 p x 32 ls
        int kk = cid >> 7, p = (cid >> 5) & 3, ls = cid & 31;
        int s = s0 + ls, tile = s >> rpt_shift, r = s & rmask;
        uint4 w = *(const uint4*)&buf[ls][kk * 32 + p * 8];
        size_t slot = ((((size_t)(b * ntiles + tile) * NK + kk) * 4 + p) << rpt_shift) + r;
        *(uint4*)&dst[slot * 8] = w;
    }
}

// ---------------- Main kernel ----------------
__global__ __launch_bounds__(256, 2)
void mp_match_main(const unsigned short* __restrict__ Apk, const unsigned short* __restrict__ Bpk,
                   const float* __restrict__ km, float* __restrict__ out)
{
    __shared__ __attribute__((aligned(16))) unsigned short Ash[2][4][BM][8]; // 16 KB
    __shared__ __attribute__((aligned(16))) unsigned short Bsh[2][4][BN][8]; // 32 KB
    __shared__ float kmf[DD];                                                // 2 KB
    __shared__ __attribute__((aligned(16))) float maxbuf[2][BM];             // 1 KB

    const int ttile = blockIdx.x;   // 0..1
    const int m     = blockIdx.y;   // 0..19
    const int b     = blockIdx.z;   // 0..31

    const int tid  = threadIdx.x;
    const int w    = tid >> 6;
    const int lane = tid & 63;
    const int l15  = lane & 15;
    const int l4   = lane >> 4;
    const int wt   = (w & 1) * 64;
    const int wsi  = w >> 1;

    // km row (fp32) -> LDS
    kmf[tid]       = km[(size_t)m * DD + tid];
    kmf[tid + 256] = km[(size_t)m * DD + tid + 256];
    __syncthreads();

    const unsigned short* apB = Apk + (size_t)(b * 2 + ttile) * (NK * 4 * BM * 8); // 65536/pair
    const unsigned short* bpB = Bpk + (size_t)b * (NK * 4 * BN * 8);               // 131072/b

    uint4 areg0, areg1;

    auto issueB = [&](int kk, int buf) {
        const unsigned short* src = bpB + (size_t)kk * (4 * BN * 8);
#pragma unroll
        for (int q = 0; q < 4; ++q)
            async_ld16(src + (size_t)(q * 256 + tid) * 8, &Bsh[buf][q][w * 64][0]);
    };
    auto issueA = [&](int kk) {
        const unsigned short* src = apB + (size_t)kk * (4 * BM * 8);
        areg0 = *(const uint4*)(src + (size_t)tid * 8);
        areg1 = *(const uint4*)(src + (size_t)(tid + 256) * 8);
    };
    auto scaleWrite = [&](int kk, int buf) {
        const int kb = kk * 32;
#pragma unroll
        for (int s = 0; s < 2; ++s) {
            int slot = tid + s * 256;
            int p = slot >> 7, r = slot & 127;
            uint4 a = s ? areg1 : areg0;
            const float* kp = &kmf[kb + p * 8];
            uint4 o;
            o.x = mulpack(a.x, kp[0], kp[1]);
            o.y = mulpack(a.y, kp[2], kp[3]);
            o.z = mulpack(a.z, kp[4], kp[5]);
            o.w = mulpack(a.w, kp[6], kp[7]);
            *(uint4*)&Ash[buf][p][r][0] = o;
        }
    };

    f32x4 acc[4][8] = {};

    issueB(0, 0);
    issueA(0);

    for (int kk = 0; kk < NK; ++kk) {
        const int buf = kk & 1;
        scaleWrite(kk, buf);      // waits on areg loads; writes A tile for this step
        __syncthreads();          // drains B DMA (vmcnt) + A ds_writes (lgkm) for `buf`
        if (kk + 1 < NK) {
            issueB(kk + 1, buf ^ 1);   // in flight during MFMA below
            issueA(kk + 1);
        }
        bf16x8 af[4], bv[8];
#pragma unroll
        for (int i = 0; i < 4; ++i)
            af[i] = *(const bf16x8*)&Ash[buf][l4][wt + i * 16 + l15][0];
#pragma unroll
        for (int j = 0; j < 8; ++j)
            bv[j] = *(const bf16x8*)&Bsh[buf][l4][wsi * 128 + j * 16 + l15][0];
#pragma unroll
        for (int i = 0; i < 4; ++i)
#pragma unroll
            for (int j = 0; j < 8; ++j)
                acc[i][j] = __builtin_amdgcn_mfma_f32_16x16x32_bf16(af[i], bv[j], acc[i][j], 0, 0, 0);
    }

    // ---- Epilogue: max over s, then tanh. C layout: col(s)=lane&15, row(t)=(lane>>4)*4+reg.
#pragma unroll
    for (int i = 0; i < 4; ++i) {
        f32x4 v = acc[i][0];
#pragma unroll
        for (int j = 1; j < 8; ++j) {
            v.x = fmaxf(v.x, acc[i][j].x);
            v.y = fmaxf(v.y, acc[i][j].y);
            v.z = fmaxf(v.z, acc[i][j].z);
            v.w = fmaxf(v.w, acc[i][j].w);
        }
#pragma unroll
        for (int off = 1; off < 16; off <<= 1) {
            v.x = fmaxf(v.x, __shfl_xor(v.x, off, 64));
            v.y = fmaxf(v.y, __shfl_xor(v.y, off, 64));
            v.z = fmaxf(v.z, __shfl_xor(v.z, off, 64));
            v.w = fmaxf(v.w, __shfl_xor(v.w, off, 64));
        }
        if (l15 == 0)
            *(f32x4*)&maxbuf[wsi][wt + i * 16 + l4 * 4] = v;
    }
    __syncthreads();
    if (tid < BM) {
        float v = fmaxf(maxbuf[0][tid], maxbuf[1][tid]);
        out[((size_t)b * TT + blockIdx.x * BM + tid) * NM + m] = tanhf(v);
    }
}

// ---------------- Fallback (R1 known-good, fp32 register staging) ----------------
__global__ __launch_bounds__(256, 2)
void mp_match_kernel(const float* __restrict__ lt, const float* __restrict__ rt,
                     const float* __restrict__ km, float* __restrict__ out)
{
    __shared__ __attribute__((aligned(16))) unsigned short Ash[2][4][BM][8];
    __shared__ __attribute__((aligned(16))) unsigned short Bsh[2][4][BN][8];
    __shared__ __attribute__((aligned(16))) float maxbuf[2][BM];

    const int ttile = blockIdx.x, m = blockIdx.y, b = blockIdx.z;
    const int t0 = ttile * BM;
    const int tid = threadIdx.x, wave = tid >> 6, lane = tid & 63;
    const int l15 = lane & 15, l4 = lane >> 4;
    const int wt = (wave & 1) * 64, wsi = wave >> 1;

    const float* ltp = lt + ((size_t)b * TT + t0) * DD;
    const float* rtp = rt + (size_t)b * TT * DD;
    const float* kmp = km + (size_t)m * DD;
    const int a_t = tid >> 1, a_h = tid & 1;

    f32x4 acc[4][8] = {};

    auto stage = [&](int kk, int buf) {
        const int d0 = kk * BK;
        const float* ap = ltp + (size_t)a_t * DD + d0 + a_h * 16;
        const float* kp = kmp + d0 + a_h * 16;
#pragma unroll
        for (int q = 0; q < 2; ++q) {
            float4 x0 = *(const float4*)(ap + q * 8);
            float4 x1 = *(const float4*)(ap + q * 8 + 4);
            float4 k0 = *(const float4*)(kp + q * 8);
            float4 k1 = *(const float4*)(kp + q * 8 + 4);
            uint4 wv;
            wv.x = pack_bf16(x0.x * k0.x, x0.y * k0.y);
            wv.y = pack_bf16(x0.z * k0.z, x0.w * k0.w);
            wv.z = pack_bf16(x1.x * k1.x, x1.y * k1.y);
            wv.w = pack_bf16(x1.z * k1.z, x1.w * k1.w);
            *(uint4*)&Ash[buf][a_h * 2 + q][a_t][0] = wv;
        }
        const float* bp = rtp + (size_t)tid * DD + d0;
#pragma unroll
        for (int p = 0; p < 4; ++p) {
            float4 y0 = *(const float4*)(bp + p * 8);
            float4 y1 = *(const float4*)(bp + p * 8 + 4);
            uint4 wv;
            wv.x = pack_bf16(y0.x, y0.y);
            wv.y = pack_bf16(y0.z, y0.w);
            wv.z = pack_bf16(y1.x, y1.y);
            wv.w = pack_bf16(y1.z, y1.w);
            *(uint4*)&Bsh[buf][p][tid][0] = wv;
        }
    };

    stage(0, 0);
    for (int kk = 0; kk < NK; ++kk) {
        const int buf = kk & 1;
        __syncthreads();
        bf16x8 af[4], bfv[8];
#pragma unroll
        for (int i = 0; i < 4; ++i)
            af[i] = *(const bf16x8*)&Ash[buf][l4][wt + i * 16 + l15][0];
#pragma unroll
        for (int j = 0; j < 8; ++j)
            bfv[j] = *(const bf16x8*)&Bsh[buf][l4][wsi * 128 + j * 16 + l15][0];
        if (kk + 1 < NK) stage(kk + 1, buf ^ 1);
#pragma unroll
        for (int i = 0; i < 4; ++i)
#pragma unroll
            for (int j = 0; j < 8; ++j)
                acc[i][j] = __builtin_amdgcn_mfma_f32_16x16x32_bf16(af[i], bfv[j], acc[i][j], 0, 0, 0);
    }
#pragma unroll
    for (int i = 0; i < 4; ++i) {
        f32x4 v = acc[i][0];
#pragma unroll
        for (int j = 1; j < 8; ++j) {
            v.x = fmaxf(v.x, acc[i][j].x); v.y = fmaxf(v.y, acc[i][j].y);
            v.z = fmaxf(v.z, acc[i][j].z); v.w = fmaxf(v.w, acc[i][j].w);
        }
#pragma unroll
        for (int off = 1; off < 16; off <<= 1) {
            v.x = fmaxf(v.x, __shfl_xor(v.x, off, 64));
            v.y = fmaxf(v.y, __shfl_xor(v.y, off, 64));
            v.z = fmaxf(v.z, __shfl_xor(v.z, off, 64));
            v.w = fmaxf(v.w, __shfl_xor(v.w, off, 64));
        }
        if (l15 == 0) *(f32x4*)&maxbuf[wsi][wt + i * 16 + l4 * 4] = v;
    }
    __syncthreads();
    if (tid < BM) {
        float v = fmaxf(maxbuf[0][tid], maxbuf[1][tid]);
        out[((size_t)b * TT + t0 + tid) * NM + m] = tanhf(v);
    }
}

extern "C" void kernel_launch(void* const* d_in, const int* in_sizes, int n_in,
                              void* d_out, int out_size, void* d_ws, size_t ws_size,
                              hipStream_t stream) {
    const float* lt  = (const float*)d_in[0];   // (32,256,512) fp32
    const float* rt  = (const float*)d_in[1];   // (32,256,512) fp32
    const float* km  = (const float*)d_in[2];   // (20,512) fp32
    float*       out = (float*)d_out;           // (32,256,20) fp32

    const size_t apk_elems = (size_t)NB * 2 * NK * 4 * BM * 8;  // 4,194,304 ushorts = 8 MB
    const size_t bpk_elems = (size_t)NB * 1 * NK * 4 * BN * 8;  // 4,194,304 ushorts = 8 MB
    const size_t need = (apk_elems + bpk_elems) * sizeof(unsigned short);  // 16 MB

    dim3 grid(TT / BM, NM, NB);   // (2, 20, 32)
    if (ws_size >= need) {
        unsigned short* Apk = (unsigned short*)d_ws;
        unsigned short* Bpk = Apk + apk_elems;
        pack_tiles<<<NB * 8, 256, 0, stream>>>(lt, Apk, 7);   // lt: 2 tiles of 128 rows
        pack_tiles<<<NB * 8, 256, 0, stream>>>(rt, Bpk, 8);   // rt: 1 tile of 256 rows
        mp_match_main<<<grid, 256, 0, stream>>>(Apk, Bpk, km, out);
    } else {
        mp_match_kernel<<<grid, 256, 0, stream>>>(lt, rt, km, out);
    }
}